// Round 6
// baseline (203.600 us; speedup 1.0000x reference)
//
#include <hip/hip_runtime.h>

typedef _Float16 v8h __attribute__((ext_vector_type(8)));
typedef float    v4f __attribute__((ext_vector_type(4)));

#define MFMA16(a, b, c) __builtin_amdgcn_mfma_f32_16x16x32_f16((a), (b), (c), 0, 0, 0)

// Direct global->LDS, 16B per lane; LDS dest is wave-uniform base + lane*16,
// so LDS stays LINEAR and the bank-swizzle is done by permuting the per-lane
// GLOBAL source address (same involution on the read side): 16B-granule j of
// row r lives at LDS granule j^(r&7) within its 128B-aligned group of 8.
#define GLL16(gptr, lptr)                                                        \
  __builtin_amdgcn_global_load_lds((const __attribute__((address_space(1))) void*)(gptr), \
                                   (__attribute__((address_space(3))) void*)(lptr), 16, 0, 0)

// Weight-fragment table in d_ws: 154 fragments, layout [frag][lane] of 8 x f16 (16B).
// Non-zero 32(k) x 16(n) tiles of the 480x480 block-diagonal Wbig:
//   ot 0..7   (cols   0..127): kt 0..3   fbase = ot*4
//   ot 8..19  (cols 128..319): kt 4..9   fbase = 32 + (ot-8)*6
//   ot 20..29 (cols 320..479): kt 10..14 fbase = 104 + (ot-20)*5
// Fragment element convention (A and B slots identical): lane l, elem e holds
// k = kt*32 + (l>>4)*8 + e; other dim = l&15.
// SWAPPED use: W-frag in A slot, x-frag in B slot -> D[m'][n'] = out^T:
// lane l, reg j = out[row l&15][col ot*16 + (l>>4)*4 + j]  -> float4 store.

__global__ void build_frags_k(const float* __restrict__ W0, const float* __restrict__ W1,
                              const float* __restrict__ W2, v8h* __restrict__ frag) {
  const int f = blockIdx.x;
  const int lane = threadIdx.x;
  int ot, kt;
  if (f < 32)       { ot = f >> 2;           kt = f & 3; }
  else if (f < 104) { int q = f - 32;  ot = 8 + q / 6;  kt = 4 + q % 6; }
  else              { int q = f - 104; ot = 20 + q / 5; kt = 10 + q % 5; }
  const int n  = ot * 16 + (lane & 15);
  const int kb = kt * 32 + (lane >> 4) * 8;
  v8h v;
#pragma unroll
  for (int e = 0; e < 8; ++e) {
    const int k = kb + e;
    float wv = 0.0f;
    if (k < 128) {
      if (n < 128) wv = W0[k * 128 + n] * 0.08838834764831845f;           // 1/sqrt(128)
    } else if (k < 320) {
      if (n >= 128 && n < 320) {
        const int i = k - 128, o = n - 128;
        if (i % 3 == o % 3) wv = W1[(i / 3) * 64 + (o / 3)] * 0.125f;     // 1/sqrt(64)
      }
    } else {
      if (n >= 320) {
        const int i = k - 320, o = n - 320;
        if (i % 5 == o % 5) wv = W2[(i / 5) * 32 + (o / 5)] * 0.17677669529663687f; // 1/sqrt(32)
      }
    }
    v[e] = (_Float16)wv;
  }
  frag[f * 64 + lane] = v;
}

// 128 threads (2 waves), 16 rows, 30720B LDS (f32, linear + src-swizzled).
// gll staging has no dest VGPRs -> whole 30KB tile queued immediately.
// Fully-unrolled ot loops let the compiler hoist all B-fragment L2 loads of a
// col-block (the round-5 limiter: un-pipelined 200cy L2 chains). Swapped MFMA
// operands give per-lane row-contiguous C/D -> one dwordx4 store per ot.
__global__ __launch_bounds__(128, 2) void irrep_linear_k(
    const float* __restrict__ x, const v8h* __restrict__ frag, float* __restrict__ out) {
  __shared__ __align__(16) unsigned char sm[30720];
  const int t    = threadIdx.x;
  const int lane = t & 63;
  const int wid  = t >> 6;
  const size_t wt = blockIdx.x;              // 16-row tile index

  // ---- stage: 16 rows x 1920B, direct to LDS with source-side swizzle ----
  {
    const unsigned char* xt = (const unsigned char*)x + wt * 30720u;
#pragma unroll
    for (int i = 0; i < 15; ++i) {
      const unsigned s   = (unsigned)(wid * 15360 + i * 1024 + lane * 16);
      const unsigned r   = s / 1920u;
      const unsigned j   = (s - r * 1920u) >> 4;
      const unsigned jg  = j ^ (r & 7u);     // involution within 128B group
      GLL16(xt + r * 1920u + (jg << 4), sm + (wid * 15360 + i * 1024));
    }
  }
  __syncthreads();

  const int par = wid;                       // wave -> ot parity
  const int r16 = lane & 15;
  const int g   = lane >> 4;
  const unsigned rb = (unsigned)r16 * 1920u;
  const unsigned q  = (unsigned)(r16 & 7);
  const unsigned char* smc = sm;

  // x-fragment for k-tile kt: lane reads 8 f32 at row r16, cols kt*32+g*8
  // = granules {kt*8+g*2, +1}, each at LDS granule (j ^ q) within its group.
#define LDAF(kt, dst)                                                              \
  {                                                                                \
    const unsigned j0 = (unsigned)((kt) * 8 + g * 2);                              \
    const float4 lo = *reinterpret_cast<const float4*>(smc + rb + ((j0 ^ q) << 4));        \
    const float4 hi = *reinterpret_cast<const float4*>(smc + rb + (((j0 + 1) ^ q) << 4));  \
    v8h v_;                                                                        \
    v_[0] = (_Float16)lo.x; v_[1] = (_Float16)lo.y;                                \
    v_[2] = (_Float16)lo.z; v_[3] = (_Float16)lo.w;                                \
    v_[4] = (_Float16)hi.x; v_[5] = (_Float16)hi.y;                                \
    v_[6] = (_Float16)hi.z; v_[7] = (_Float16)hi.w;                                \
    dst = v_;                                                                      \
  }

  // lane's output base: row (wt*16 + r16), col g*4
  float* const obase = out + (wt * 16 + (size_t)r16) * 480 + (size_t)g * 4;

  {  // cols 0..127, K-tiles 0..3
    v8h a0, a1, a2, a3;
    LDAF(0, a0) LDAF(1, a1) LDAF(2, a2) LDAF(3, a3)
#pragma unroll
    for (int ot = par; ot < 8; ot += 2) {
      const v8h* bp = frag + ot * 4 * 64 + lane;
      v4f acc = {0.f, 0.f, 0.f, 0.f};
      acc = MFMA16(bp[0],   a0, acc);
      acc = MFMA16(bp[64],  a1, acc);
      acc = MFMA16(bp[128], a2, acc);
      acc = MFMA16(bp[192], a3, acc);
      *reinterpret_cast<v4f*>(obase + ot * 16) = acc;
    }
  }
  {  // cols 128..319, K-tiles 4..9
    v8h a4, a5, a6, a7, a8, a9;
    LDAF(4, a4) LDAF(5, a5) LDAF(6, a6) LDAF(7, a7) LDAF(8, a8) LDAF(9, a9)
#pragma unroll
    for (int ot = 8 + par; ot < 20; ot += 2) {
      const v8h* bp = frag + (32 + (ot - 8) * 6) * 64 + lane;
      v4f acc = {0.f, 0.f, 0.f, 0.f};
      acc = MFMA16(bp[0],   a4, acc);
      acc = MFMA16(bp[64],  a5, acc);
      acc = MFMA16(bp[128], a6, acc);
      acc = MFMA16(bp[192], a7, acc);
      acc = MFMA16(bp[256], a8, acc);
      acc = MFMA16(bp[320], a9, acc);
      *reinterpret_cast<v4f*>(obase + ot * 16) = acc;
    }
  }
  {  // cols 320..479, K-tiles 10..14
    v8h aA, aB, aC, aD, aE;
    LDAF(10, aA) LDAF(11, aB) LDAF(12, aC) LDAF(13, aD) LDAF(14, aE)
#pragma unroll
    for (int ot = 20 + par; ot < 30; ot += 2) {
      const v8h* bp = frag + (104 + (ot - 20) * 5) * 64 + lane;
      v4f acc = {0.f, 0.f, 0.f, 0.f};
      acc = MFMA16(bp[0],   aA, acc);
      acc = MFMA16(bp[64],  aB, acc);
      acc = MFMA16(bp[128], aC, acc);
      acc = MFMA16(bp[192], aD, acc);
      acc = MFMA16(bp[256], aE, acc);
      *reinterpret_cast<v4f*>(obase + ot * 16) = acc;
    }
  }
#undef LDAF
}

extern "C" void kernel_launch(void* const* d_in, const int* in_sizes, int n_in,
                              void* d_out, int out_size, void* d_ws, size_t ws_size,
                              hipStream_t stream) {
  const float* x  = (const float*)d_in[0];
  const float* W0 = (const float*)d_in[1];
  const float* W1 = (const float*)d_in[2];
  const float* W2 = (const float*)d_in[3];
  float* out = (float*)d_out;
  v8h* frag = (v8h*)d_ws;   // 154 * 64 * 16 B = 157,696 B

  build_frags_k<<<154, 64, 0, stream>>>(W0, W1, W2, frag);

  const int N = in_sizes[0] / 480;      // 200000
  const int nblk = N / 16;              // 12500 tiles, one per block
  irrep_linear_k<<<nblk, 128, 0, stream>>>(x, frag, out);
}

// Round 7
// 177.239 us; speedup vs baseline: 1.1487x; 1.1487x over previous
//
#include <hip/hip_runtime.h>

typedef _Float16 v8h __attribute__((ext_vector_type(8)));
typedef float    v4f __attribute__((ext_vector_type(4)));

#define MFMA16(a, b, c) __builtin_amdgcn_mfma_f32_16x16x32_f16((a), (b), (c), 0, 0, 0)

// Direct global->LDS, 16B per lane; LDS dest is wave-uniform base + lane*16,
// so LDS stays LINEAR and the bank-swizzle is done by permuting the per-lane
// GLOBAL source address (same involution on the read side): 16B-granule j of
// row r lives at LDS granule j^(r&7) within its 128B-aligned group of 8.
#define GLL16(gptr, lptr)                                                        \
  __builtin_amdgcn_global_load_lds((const __attribute__((address_space(1))) void*)(gptr), \
                                   (__attribute__((address_space(3))) void*)(lptr), 16, 0, 0)

// Weight-fragment table in d_ws: 154 fragments, layout [frag][lane] of 8 x f16 (16B).
// Non-zero 32(k) x 16(n) tiles of the 480x480 block-diagonal Wbig:
//   ot 0..7   (cols   0..127): kt 0..3   fbase = ot*4
//   ot 8..19  (cols 128..319): kt 4..9   fbase = 32 + (ot-8)*6
//   ot 20..29 (cols 320..479): kt 10..14 fbase = 104 + (ot-20)*5
// Fragment element convention (A and B slots identical): lane l, elem e holds
// k = kt*32 + (l>>4)*8 + e; other dim = l&15.
// SWAPPED use: W-frag in A slot, x-frag in B slot -> lane l, reg j =
// out[row l&15][col ot*16 + (l>>4)*4 + j] -> one float4 store per ot per slab.

__global__ void build_frags_k(const float* __restrict__ W0, const float* __restrict__ W1,
                              const float* __restrict__ W2, v8h* __restrict__ frag) {
  const int f = blockIdx.x;
  const int lane = threadIdx.x;
  int ot, kt;
  if (f < 32)       { ot = f >> 2;           kt = f & 3; }
  else if (f < 104) { int q = f - 32;  ot = 8 + q / 6;  kt = 4 + q % 6; }
  else              { int q = f - 104; ot = 20 + q / 5; kt = 10 + q % 5; }
  const int n  = ot * 16 + (lane & 15);
  const int kb = kt * 32 + (lane >> 4) * 8;
  v8h v;
#pragma unroll
  for (int e = 0; e < 8; ++e) {
    const int k = kb + e;
    float wv = 0.0f;
    if (k < 128) {
      if (n < 128) wv = W0[k * 128 + n] * 0.08838834764831845f;           // 1/sqrt(128)
    } else if (k < 320) {
      if (n >= 128 && n < 320) {
        const int i = k - 128, o = n - 128;
        if (i % 3 == o % 3) wv = W1[(i / 3) * 64 + (o / 3)] * 0.125f;     // 1/sqrt(64)
      }
    } else {
      if (n >= 320) {
        const int i = k - 320, o = n - 320;
        if (i % 5 == o % 5) wv = W2[(i / 5) * 32 + (o / 5)] * 0.17677669529663687f; // 1/sqrt(32)
      }
    }
    v[e] = (_Float16)wv;
  }
  frag[f * 64 + lane] = v;
}

// 256 threads (4 waves), 32 rows, 61440B LDS -> 2 blocks/CU (8 waves, 2/SIMD).
// Waves split ot 4-ways (ot = w mod 4); each wave applies each B-fragment to
// TWO 16-row slabs held in registers -> fragment L2/L3 traffic per output row
// is HALVED vs rounds 1-6 (the shared ~4 TB/s limiter), and each B-load feeds
// 2 independent MFMAs. x staged via global_load_lds (no dest VGPRs, whole
// tile queued immediately) with source-side bank swizzle.
__global__ __launch_bounds__(256, 2) void irrep_linear_k(
    const float* __restrict__ x, const v8h* __restrict__ frag, float* __restrict__ out) {
  __shared__ __align__(16) unsigned char sm[61440];
  const int t    = threadIdx.x;
  const int lane = t & 63;
  const int w    = t >> 6;                   // wave id 0..3 -> ot residue
  const size_t wt = blockIdx.x;              // 32-row tile index

  // ---- stage: 32 rows x 1920B, direct to LDS with source-side swizzle ----
  {
    const unsigned char* xt = (const unsigned char*)x + wt * 61440u;
#pragma unroll
    for (int i = 0; i < 15; ++i) {
      const unsigned s  = (unsigned)(i * 4096 + w * 1024 + lane * 16);
      const unsigned r  = s / 1920u;
      const unsigned j  = (s - r * 1920u) >> 4;
      GLL16(xt + r * 1920u + ((j ^ (r & 7u)) << 4), sm + (i * 4096 + w * 1024));
    }
  }
  __syncthreads();

  const int r16 = lane & 15;
  const int g   = lane >> 4;
  const unsigned char* smc = sm;

  // x-fragment for slab sl, k-tile kt: lane reads 8 f32 at row sl*16+r16,
  // granules {kt*8+g*2, +1}, each at LDS granule (j ^ (row&7)) in its group.
#define LDAF(sl, kt, dst)                                                          \
  {                                                                                \
    const unsigned row = (unsigned)((sl) * 16 + r16);                              \
    const unsigned rb  = row * 1920u;                                              \
    const unsigned q   = row & 7u;                                                 \
    const unsigned j0  = (unsigned)((kt) * 8 + g * 2);                             \
    const float4 lo = *reinterpret_cast<const float4*>(smc + rb + ((j0 ^ q) << 4));        \
    const float4 hi = *reinterpret_cast<const float4*>(smc + rb + (((j0 + 1) ^ q) << 4));  \
    v8h v_;                                                                        \
    v_[0] = (_Float16)lo.x; v_[1] = (_Float16)lo.y;                                \
    v_[2] = (_Float16)lo.z; v_[3] = (_Float16)lo.w;                                \
    v_[4] = (_Float16)hi.x; v_[5] = (_Float16)hi.y;                                \
    v_[6] = (_Float16)hi.z; v_[7] = (_Float16)hi.w;                                \
    dst = v_;                                                                      \
  }

  // output bases: slab0 row wt*32 + r16, slab1 += 16 rows; col g*4 (+ot*16)
  float* const o0 = out + (wt * 32 + (size_t)r16) * 480 + (size_t)g * 4;
  float* const o1 = o0 + 16 * 480;

  {  // col-block 0: cols 0..127, kt 0..3; this wave's ots: {w, w+4}
    v8h a00, a01, a02, a03, a10, a11, a12, a13;
    LDAF(0, 0, a00) LDAF(0, 1, a01) LDAF(0, 2, a02) LDAF(0, 3, a03)
    LDAF(1, 0, a10) LDAF(1, 1, a11) LDAF(1, 2, a12) LDAF(1, 3, a13)
#pragma unroll
    for (int qq = 0; qq < 2; ++qq) {
      const int ot = w + qq * 4;
      const v8h* bp = frag + ot * 4 * 64 + lane;
      const v8h b0 = bp[0], b1 = bp[64], b2 = bp[128], b3 = bp[192];
      v4f acc0 = {0.f, 0.f, 0.f, 0.f}, acc1 = {0.f, 0.f, 0.f, 0.f};
      acc0 = MFMA16(b0, a00, acc0);  acc1 = MFMA16(b0, a10, acc1);
      acc0 = MFMA16(b1, a01, acc0);  acc1 = MFMA16(b1, a11, acc1);
      acc0 = MFMA16(b2, a02, acc0);  acc1 = MFMA16(b2, a12, acc1);
      acc0 = MFMA16(b3, a03, acc0);  acc1 = MFMA16(b3, a13, acc1);
      *reinterpret_cast<v4f*>(o0 + ot * 16) = acc0;
      *reinterpret_cast<v4f*>(o1 + ot * 16) = acc1;
    }
  }
  {  // col-block 1: cols 128..319, kt 4..9; ots: {8+w, 12+w, 16+w}
    v8h a0_[6], a1_[6];
#pragma unroll
    for (int k = 0; k < 6; ++k) { LDAF(0, 4 + k, a0_[k]) LDAF(1, 4 + k, a1_[k]) }
#pragma unroll
    for (int qq = 0; qq < 3; ++qq) {
      const int ot = 8 + w + qq * 4;
      const v8h* bp = frag + (32 + (ot - 8) * 6) * 64 + lane;
      v4f acc0 = {0.f, 0.f, 0.f, 0.f}, acc1 = {0.f, 0.f, 0.f, 0.f};
#pragma unroll
      for (int k = 0; k < 6; ++k) {
        const v8h b = bp[k * 64];
        acc0 = MFMA16(b, a0_[k], acc0);
        acc1 = MFMA16(b, a1_[k], acc1);
      }
      *reinterpret_cast<v4f*>(o0 + ot * 16) = acc0;
      *reinterpret_cast<v4f*>(o1 + ot * 16) = acc1;
    }
  }
  {  // col-block 2: cols 320..479, kt 10..14; ots: {20+w, 24+w} (+ {28+w} if w<2)
    v8h a0_[5], a1_[5];
#pragma unroll
    for (int k = 0; k < 5; ++k) { LDAF(0, 10 + k, a0_[k]) LDAF(1, 10 + k, a1_[k]) }
#pragma unroll
    for (int qq = 0; qq < 2; ++qq) {
      const int ot = 20 + w + qq * 4;
      const v8h* bp = frag + (104 + (ot - 20) * 5) * 64 + lane;
      v4f acc0 = {0.f, 0.f, 0.f, 0.f}, acc1 = {0.f, 0.f, 0.f, 0.f};
#pragma unroll
      for (int k = 0; k < 5; ++k) {
        const v8h b = bp[k * 64];
        acc0 = MFMA16(b, a0_[k], acc0);
        acc1 = MFMA16(b, a1_[k], acc1);
      }
      *reinterpret_cast<v4f*>(o0 + ot * 16) = acc0;
      *reinterpret_cast<v4f*>(o1 + ot * 16) = acc1;
    }
    if (w < 2) {
      const int ot = 28 + w;
      const v8h* bp = frag + (104 + (ot - 20) * 5) * 64 + lane;
      v4f acc0 = {0.f, 0.f, 0.f, 0.f}, acc1 = {0.f, 0.f, 0.f, 0.f};
#pragma unroll
      for (int k = 0; k < 5; ++k) {
        const v8h b = bp[k * 64];
        acc0 = MFMA16(b, a0_[k], acc0);
        acc1 = MFMA16(b, a1_[k], acc1);
      }
      *reinterpret_cast<v4f*>(o0 + ot * 16) = acc0;
      *reinterpret_cast<v4f*>(o1 + ot * 16) = acc1;
    }
  }
#undef LDAF
}

extern "C" void kernel_launch(void* const* d_in, const int* in_sizes, int n_in,
                              void* d_out, int out_size, void* d_ws, size_t ws_size,
                              hipStream_t stream) {
  const float* x  = (const float*)d_in[0];
  const float* W0 = (const float*)d_in[1];
  const float* W1 = (const float*)d_in[2];
  const float* W2 = (const float*)d_in[3];
  float* out = (float*)d_out;
  v8h* frag = (v8h*)d_ws;   // 154 * 64 * 16 B = 157,696 B

  build_frags_k<<<154, 64, 0, stream>>>(W0, W1, W2, frag);

  const int N = in_sizes[0] / 480;      // 200000
  const int nblk = N / 32;              // 6250 tiles, one per block
  irrep_linear_k<<<nblk, 256, 0, stream>>>(x, frag, out);
}